// Round 5
// baseline (124.604 us; speedup 1.0000x reference)
//
#include <hip/hip_runtime.h>
#include <hip/hip_fp16.h>

#define DD 64
#define NPB 64          // nodes per block (node kernel)
#define LP 72           // padded LDS row stride in halves (144 B): 2-way-only bank aliasing

typedef _Float16 f16x8 __attribute__((ext_vector_type(8)));
typedef _Float16 f16x4 __attribute__((ext_vector_type(4)));
typedef float    f32x4 __attribute__((ext_vector_type(4)));
typedef int      i32x4 __attribute__((ext_vector_type(4)));
typedef float    fv4   __attribute__((ext_vector_type(4)));

// Node-level transform on MFMA f16 (fp32 accumulate):
//   A = (K_h + P_e) @ W1 + b1   (stored fp16)
//   B = Q_h @ W1                (stored fp16)
// 64 nodes/block, 4 waves. OPERAND-SWAPPED MFMA: A-op = W1T rows (features),
// B-op = X rows (nodes), so D[f][node] has col=lane&15 -> node, row=q*4+r ->
// feature. Each lane then holds 4 CONSECUTIVE features of one node per tile
// -> 8B dwordx2 stores (8 store instrs/wave vs 32 scattered 2B-chunk stores).
__global__ __launch_bounds__(256) void node_transform_mfma(
    const float* __restrict__ K_h, const float* __restrict__ Q_h,
    const float* __restrict__ P_e, const float* __restrict__ W1,
    const float* __restrict__ b1, __half* __restrict__ A,
    __half* __restrict__ Bm, int n_nodes)
{
    __shared__ __half XH [NPB][LP];   // fp16(K+P)
    __shared__ __half QH [NPB][LP];   // fp16(Q)
    __shared__ __half W1T[DD][LP];    // W1 transposed: W1T[n][k] = W1[k][n]

    const int tid   = threadIdx.x;
    const int nbase = blockIdx.x * NPB;

    // ---- Stage W1T (8 KB): thread t reads W1[k][n0..n0+15], scatters column-wise ----
    {
        const int k  = tid >> 2;
        const int n0 = (tid & 3) << 4;
        const float* wr = W1 + k * DD + n0;
        float4 w0 = *(const float4*)(wr);
        float4 w1v = *(const float4*)(wr + 4);
        float4 w2v = *(const float4*)(wr + 8);
        float4 w3v = *(const float4*)(wr + 12);
        const float wv[16] = {w0.x,w0.y,w0.z,w0.w, w1v.x,w1v.y,w1v.z,w1v.w,
                              w2v.x,w2v.y,w2v.z,w2v.w, w3v.x,w3v.y,w3v.z,w3v.w};
#pragma unroll
        for (int j = 0; j < 16; ++j)
            W1T[n0 + j][k] = __float2half(wv[j]);
    }

    // ---- Stage XH = fp16(K+P), QH = fp16(Q); coalesced nontemporal fv4 reads ----
#pragma unroll
    for (int ch = 0; ch < 4; ++ch) {
        int idx = tid + (ch << 8);        // float4 index over [64 rows][16]
        int r   = idx >> 4;
        int q4  = idx & 15;
        int node = nbase + r;
        fv4 kv = (fv4){0.f, 0.f, 0.f, 0.f};
        fv4 pv = kv, qv = kv;
        if (node < n_nodes) {
            kv = __builtin_nontemporal_load((const fv4*)(K_h + (size_t)node * DD + q4 * 4));
            pv = __builtin_nontemporal_load((const fv4*)(P_e + (size_t)node * DD + q4 * 4));
            qv = __builtin_nontemporal_load((const fv4*)(Q_h + (size_t)node * DD + q4 * 4));
        }
        __half2* xh = (__half2*)&XH[r][q4 << 2];
        xh[0] = __float22half2_rn(make_float2(kv[0] + pv[0], kv[1] + pv[1]));
        xh[1] = __float22half2_rn(make_float2(kv[2] + pv[2], kv[3] + pv[3]));
        __half2* qh = (__half2*)&QH[r][q4 << 2];
        qh[0] = __float22half2_rn(make_float2(qv[0], qv[1]));
        qh[1] = __float22half2_rn(make_float2(qv[2], qv[3]));
    }
    __syncthreads();

    // ---- MFMA main: wave w, lane (m = lane&15, q = lane>>4) ----
    const int w    = tid >> 6;
    const int lane = tid & 63;
    const int m    = lane & 15;
    const int q    = lane >> 4;
    const int row  = (w << 4) + m;    // node row for the B-operand fragment

    f16x8 xlo = *(const f16x8*)&XH[row][(q << 3)];
    f16x8 xhi = *(const f16x8*)&XH[row][32 + (q << 3)];
    f16x8 qlo = *(const f16x8*)&QH[row][(q << 3)];
    f16x8 qhi = *(const f16x8*)&QH[row][32 + (q << 3)];

    f32x4 accA[4], accB[4];
#pragma unroll
    for (int t = 0; t < 4; ++t) {
        // b1 fold: acc reg r corresponds to feature t*16 + q*4 + r
        float4 bv = *(const float4*)(b1 + t * 16 + (q << 2));
        accA[t] = (f32x4){bv.x, bv.y, bv.z, bv.w};
        accB[t] = (f32x4){0.f, 0.f, 0.f, 0.f};
        f16x8 wlo = *(const f16x8*)&W1T[t * 16 + m][(q << 3)];
        f16x8 whi = *(const f16x8*)&W1T[t * 16 + m][32 + (q << 3)];
        // operand-swapped: D[feature][node]
        accA[t] = __builtin_amdgcn_mfma_f32_16x16x32_f16(wlo, xlo, accA[t], 0, 0, 0);
        accA[t] = __builtin_amdgcn_mfma_f32_16x16x32_f16(whi, xhi, accA[t], 0, 0, 0);
        accB[t] = __builtin_amdgcn_mfma_f32_16x16x32_f16(wlo, qlo, accB[t], 0, 0, 0);
        accB[t] = __builtin_amdgcn_mfma_f32_16x16x32_f16(whi, qhi, accB[t], 0, 0, 0);
    }

    // ---- Store: lane holds features t*16+q*4+{0..3} of node nbase+w*16+m ----
    const int node = nbase + (w << 4) + m;
    if (node < n_nodes) {
        __half* Arow = A  + (size_t)node * DD + (q << 2);
        __half* Brow = Bm + (size_t)node * DD + (q << 2);
#pragma unroll
        for (int t = 0; t < 4; ++t) {
            f16x4 av, bvh;
#pragma unroll
            for (int r = 0; r < 4; ++r) {
                av[r]  = (_Float16)accA[t][r];
                bvh[r] = (_Float16)accB[t][r];
            }
            *(f16x4*)(Arow + t * 16) = av;    // 8B dwordx2, 8B-aligned
            *(f16x4*)(Brow + t * 16) = bvh;
        }
    }
}

// Edge-level: score[e] = relu(A[src[e]] - B[dst[e]]) . W2 + b2
// 8 lanes per edge, 4 edges (one quad) per lane-group; persistent grid with
// next-quad index prefetch; nontemporal src/dst/out streams. At the per-CU
// gather request wall (~1.5 cyc per 64B segment, 4 segments/edge) — R1 src-
// sort, R2 dst-XCD-pin, R3 prefetch all converge to ~63 us for this phase.
__global__ __launch_bounds__(256) void edge_score_kernel(
    const __half* __restrict__ A, const __half* __restrict__ Bm,
    const int* __restrict__ src, const int* __restrict__ dst,
    const float* __restrict__ W2, const float* __restrict__ b2,
    float* __restrict__ out, int n_edges)
{
    const int tid = threadIdx.x;
    const int g   = tid >> 3;                   // lane-group 0..31
    const int c   = tid & 7;                    // 16B chunk within row
    const int nq  = n_edges >> 2;               // full quads
    const int tg  = gridDim.x << 5;             // total lane-groups in grid

    float4 w0 = *(const float4*)(W2 + c * 8);   // uniform -> s_load
    float4 w1 = *(const float4*)(W2 + c * 8 + 4);
    const float wv[8] = {w0.x, w0.y, w0.z, w0.w, w1.x, w1.y, w1.z, w1.w};
    const size_t coff = (size_t)(c * 8);
    const float bb = b2[0];

    int q = (blockIdx.x << 5) + g;
    if (q < nq) {
        i32x4 sv = __builtin_nontemporal_load((const i32x4*)(src + (q << 2)));
        i32x4 dv = __builtin_nontemporal_load((const i32x4*)(dst + (q << 2)));
        for (;;) {
            const int e0 = q << 2;
            const int qn = q + tg;
            const bool more = (qn < nq);
            i32x4 svn, dvn;
            if (more) {   // prefetch next quad's indices
                svn = __builtin_nontemporal_load((const i32x4*)(src + (qn << 2)));
                dvn = __builtin_nontemporal_load((const i32x4*)(dst + (qn << 2)));
            }

            // Issue all 8 row loads back-to-back.
            float4 ra0 = *(const float4*)(A  + (size_t)sv[0] * DD + coff);
            float4 rb0 = *(const float4*)(Bm + (size_t)dv[0] * DD + coff);
            float4 ra1 = *(const float4*)(A  + (size_t)sv[1] * DD + coff);
            float4 rb1 = *(const float4*)(Bm + (size_t)dv[1] * DD + coff);
            float4 ra2 = *(const float4*)(A  + (size_t)sv[2] * DD + coff);
            float4 rb2 = *(const float4*)(Bm + (size_t)dv[2] * DD + coff);
            float4 ra3 = *(const float4*)(A  + (size_t)sv[3] * DD + coff);
            float4 rb3 = *(const float4*)(Bm + (size_t)dv[3] * DD + coff);

            float acc0 = 0.f, acc1 = 0.f, acc2 = 0.f, acc3 = 0.f;
            const __half2* ah0 = (const __half2*)&ra0;
            const __half2* bh0 = (const __half2*)&rb0;
            const __half2* ah1 = (const __half2*)&ra1;
            const __half2* bh1 = (const __half2*)&rb1;
            const __half2* ah2 = (const __half2*)&ra2;
            const __half2* bh2 = (const __half2*)&rb2;
            const __half2* ah3 = (const __half2*)&ra3;
            const __half2* bh3 = (const __half2*)&rb3;
#pragma unroll
            for (int j = 0; j < 4; ++j) {
                float2 x, y;
                x = __half22float2(ah0[j]); y = __half22float2(bh0[j]);
                acc0 = fmaf(fmaxf(x.x - y.x, 0.f), wv[2 * j + 0], acc0);
                acc0 = fmaf(fmaxf(x.y - y.y, 0.f), wv[2 * j + 1], acc0);
                x = __half22float2(ah1[j]); y = __half22float2(bh1[j]);
                acc1 = fmaf(fmaxf(x.x - y.x, 0.f), wv[2 * j + 0], acc1);
                acc1 = fmaf(fmaxf(x.y - y.y, 0.f), wv[2 * j + 1], acc1);
                x = __half22float2(ah2[j]); y = __half22float2(bh2[j]);
                acc2 = fmaf(fmaxf(x.x - y.x, 0.f), wv[2 * j + 0], acc2);
                acc2 = fmaf(fmaxf(x.y - y.y, 0.f), wv[2 * j + 1], acc2);
                x = __half22float2(ah3[j]); y = __half22float2(bh3[j]);
                acc3 = fmaf(fmaxf(x.x - y.x, 0.f), wv[2 * j + 0], acc3);
                acc3 = fmaf(fmaxf(x.y - y.y, 0.f), wv[2 * j + 1], acc3);
            }

            acc0 += __shfl_xor(acc0, 1); acc1 += __shfl_xor(acc1, 1);
            acc2 += __shfl_xor(acc2, 1); acc3 += __shfl_xor(acc3, 1);
            acc0 += __shfl_xor(acc0, 2); acc1 += __shfl_xor(acc1, 2);
            acc2 += __shfl_xor(acc2, 2); acc3 += __shfl_xor(acc3, 2);
            acc0 += __shfl_xor(acc0, 4); acc1 += __shfl_xor(acc1, 4);
            acc2 += __shfl_xor(acc2, 4); acc3 += __shfl_xor(acc3, 4);

            if (c == 0) {
                fv4 r;
                r[0] = acc0 + bb; r[1] = acc1 + bb;
                r[2] = acc2 + bb; r[3] = acc3 + bb;
                __builtin_nontemporal_store(r, (fv4*)(out + e0));
            }

            if (!more) break;
            q = qn; sv = svn; dv = dvn;
        }
    }

    // Remainder edges (n_edges % 4): block 0, lane-group 0 only.
    const int rem = n_edges & 3;
    if (rem && blockIdx.x == 0 && g == 0) {
        for (int e = n_edges - rem; e < n_edges; ++e) {
            int s = src[e], d = dst[e];
            float4 ar = *(const float4*)(A  + (size_t)s * DD + coff);
            float4 br = *(const float4*)(Bm + (size_t)d * DD + coff);
            const __half2* ah = (const __half2*)&ar;
            const __half2* bh = (const __half2*)&br;
            float acc = 0.f;
#pragma unroll
            for (int j = 0; j < 4; ++j) {
                float2 x = __half22float2(ah[j]);
                float2 y = __half22float2(bh[j]);
                acc = fmaf(fmaxf(x.x - y.x, 0.f), wv[2 * j + 0], acc);
                acc = fmaf(fmaxf(x.y - y.y, 0.f), wv[2 * j + 1], acc);
            }
            acc += __shfl_xor(acc, 1);
            acc += __shfl_xor(acc, 2);
            acc += __shfl_xor(acc, 4);
            if (c == 0) out[e] = acc + bb;
        }
    }
}

extern "C" void kernel_launch(void* const* d_in, const int* in_sizes, int n_in,
                              void* d_out, int out_size, void* d_ws, size_t ws_size,
                              hipStream_t stream) {
    const float* K_h = (const float*)d_in[0];
    const float* Q_h = (const float*)d_in[1];
    const float* P_e = (const float*)d_in[2];
    const int*   src = (const int*)d_in[3];
    const int*   dst = (const int*)d_in[4];
    const float* W1  = (const float*)d_in[5];
    const float* b1  = (const float*)d_in[6];
    const float* W2  = (const float*)d_in[7];
    const float* b2  = (const float*)d_in[8];
    float* out = (float*)d_out;

    int n_nodes = in_sizes[0] / DD;
    int n_edges = in_sizes[3];

    // Workspace: A [n][64] fp16, B [n][64] fp16 (12.8 MB total)
    __half* A  = (__half*)d_ws;
    __half* Bm = A + (size_t)n_nodes * DD;

    node_transform_mfma<<<(n_nodes + NPB - 1) / NPB, 256, 0, stream>>>(
        K_h, Q_h, P_e, W1, b1, A, Bm, n_nodes);

    // Persistent grid: 2048 blocks (8 blocks/CU target), 32 lane-groups each,
    // grid-stride over edge-quads with index prefetch.
    int nq = n_edges >> 2;
    int grid = (nq + 31) >> 5;
    if (grid > 2048) grid = 2048;
    if (grid < 1) grid = 1;
    edge_score_kernel<<<grid, 256, 0, stream>>>(
        A, Bm, src, dst, W2, b2, out, n_edges);
}

// Round 6
// 120.840 us; speedup vs baseline: 1.0311x; 1.0311x over previous
//
#include <hip/hip_runtime.h>
#include <hip/hip_fp16.h>

#define DD 64
#define NPB 64          // nodes per block (node kernel)
#define LP 72           // padded LDS row stride in halves (144 B): 2-way-only bank aliasing

typedef _Float16 f16x8 __attribute__((ext_vector_type(8)));
typedef float    f32x4 __attribute__((ext_vector_type(4)));
typedef int      i32x4 __attribute__((ext_vector_type(4)));
typedef float    fv4   __attribute__((ext_vector_type(4)));

// Node-level transform on MFMA f16 (fp32 accumulate):
//   A = (K_h + P_e) @ W1 + b1   (stored fp16)
//   B = Q_h @ W1                (stored fp16)
// 64 nodes/block, 4 waves; wave w computes rows w*16..w*16+15 of BOTH outputs
// via 16x16x32 MFMA (2 k-halves x 4 col-tiles x {A,B} = 16 mfma/wave).
// R5 falsified the operand-swapped writeback (32B store segments either way);
// this is the R3-proven layout.
__global__ __launch_bounds__(256) void node_transform_mfma(
    const float* __restrict__ K_h, const float* __restrict__ Q_h,
    const float* __restrict__ P_e, const float* __restrict__ W1,
    const float* __restrict__ b1, __half* __restrict__ A,
    __half* __restrict__ Bm, int n_nodes)
{
    __shared__ __half XH [NPB][LP];   // fp16(K+P)
    __shared__ __half QH [NPB][LP];   // fp16(Q)
    __shared__ __half W1T[DD][LP];    // W1 transposed: W1T[n][k] = W1[k][n]

    const int tid   = threadIdx.x;
    const int nbase = blockIdx.x * NPB;

    // ---- Stage W1T (8 KB): thread t reads W1[k][n0..n0+15], scatters column-wise ----
    {
        const int k  = tid >> 2;
        const int n0 = (tid & 3) << 4;
        const float* wr = W1 + k * DD + n0;
        float4 w0 = *(const float4*)(wr);
        float4 w1v = *(const float4*)(wr + 4);
        float4 w2v = *(const float4*)(wr + 8);
        float4 w3v = *(const float4*)(wr + 12);
        const float wv[16] = {w0.x,w0.y,w0.z,w0.w, w1v.x,w1v.y,w1v.z,w1v.w,
                              w2v.x,w2v.y,w2v.z,w2v.w, w3v.x,w3v.y,w3v.z,w3v.w};
#pragma unroll
        for (int j = 0; j < 16; ++j)
            W1T[n0 + j][k] = __float2half(wv[j]);
    }

    // ---- Stage XH = fp16(K+P), QH = fp16(Q); coalesced float4 global reads ----
#pragma unroll
    for (int ch = 0; ch < 4; ++ch) {
        int idx = tid + (ch << 8);        // float4 index over [64 rows][16]
        int r   = idx >> 4;
        int q4  = idx & 15;
        int node = nbase + r;
        float4 kv = make_float4(0.f,0.f,0.f,0.f);
        float4 pv = kv, qv = kv;
        if (node < n_nodes) {
            kv = *(const float4*)(K_h + (size_t)node * DD + q4 * 4);
            pv = *(const float4*)(P_e + (size_t)node * DD + q4 * 4);
            qv = *(const float4*)(Q_h + (size_t)node * DD + q4 * 4);
        }
        __half2* xh = (__half2*)&XH[r][q4 << 2];
        xh[0] = __float22half2_rn(make_float2(kv.x + pv.x, kv.y + pv.y));
        xh[1] = __float22half2_rn(make_float2(kv.z + pv.z, kv.w + pv.w));
        __half2* qh = (__half2*)&QH[r][q4 << 2];
        qh[0] = __float22half2_rn(make_float2(qv.x, qv.y));
        qh[1] = __float22half2_rn(make_float2(qv.z, qv.w));
    }
    __syncthreads();

    // ---- MFMA main: wave w, lane (m = lane&15, q = lane>>4) ----
    const int w    = tid >> 6;
    const int lane = tid & 63;
    const int m    = lane & 15;
    const int q    = lane >> 4;
    const int row  = (w << 4) + m;

    f16x8 xlo = *(const f16x8*)&XH[row][(q << 3)];
    f16x8 xhi = *(const f16x8*)&XH[row][32 + (q << 3)];
    f16x8 qlo = *(const f16x8*)&QH[row][(q << 3)];
    f16x8 qhi = *(const f16x8*)&QH[row][32 + (q << 3)];

    f32x4 accA[4], accB[4];
#pragma unroll
    for (int t = 0; t < 4; ++t) {
        float bb = b1[t * 16 + m];            // b1 folded into A accumulator
        accA[t] = (f32x4){bb, bb, bb, bb};
        accB[t] = (f32x4){0.f, 0.f, 0.f, 0.f};
        f16x8 wlo = *(const f16x8*)&W1T[t * 16 + m][(q << 3)];
        f16x8 whi = *(const f16x8*)&W1T[t * 16 + m][32 + (q << 3)];
        accA[t] = __builtin_amdgcn_mfma_f32_16x16x32_f16(xlo, wlo, accA[t], 0, 0, 0);
        accA[t] = __builtin_amdgcn_mfma_f32_16x16x32_f16(xhi, whi, accA[t], 0, 0, 0);
        accB[t] = __builtin_amdgcn_mfma_f32_16x16x32_f16(qlo, wlo, accB[t], 0, 0, 0);
        accB[t] = __builtin_amdgcn_mfma_f32_16x16x32_f16(qhi, whi, accB[t], 0, 0, 0);
    }

    // ---- Store: acc[t][r] -> out[nbase + w*16 + q*4 + r][t*16 + m] ----
#pragma unroll
    for (int r = 0; r < 4; ++r) {
        int node = nbase + (w << 4) + (q << 2) + r;
        if (node >= n_nodes) continue;
        __half* Arow = A  + (size_t)node * DD + m;
        __half* Brow = Bm + (size_t)node * DD + m;
#pragma unroll
        for (int t = 0; t < 4; ++t) {
            Arow[t * 16] = __float2half(accA[t][r]);
            Brow[t * 16] = __float2half(accB[t][r]);
        }
    }
}

// Edge-level: score[e] = relu(A[src[e]] - B[dst[e]]) . W2 + b2
// 8 lanes per edge, 4 edges (one quad) per lane-group; persistent grid
// (2048 blocks) grid-striding over quads with next-quad index prefetch;
// nontemporal src/dst/out streams. At the per-CU gather request wall
// (~1.5 cyc per 64B segment, 4 segments/edge): R1 src-sort, R2 dst-XCD-pin,
// R3 prefetch all converge to ~63 us for this phase.
__global__ __launch_bounds__(256) void edge_score_kernel(
    const __half* __restrict__ A, const __half* __restrict__ Bm,
    const int* __restrict__ src, const int* __restrict__ dst,
    const float* __restrict__ W2, const float* __restrict__ b2,
    float* __restrict__ out, int n_edges)
{
    const int tid = threadIdx.x;
    const int g   = tid >> 3;                   // lane-group 0..31
    const int c   = tid & 7;                    // 16B chunk within row
    const int nq  = n_edges >> 2;               // full quads
    const int tg  = gridDim.x << 5;             // total lane-groups in grid

    float4 w0 = *(const float4*)(W2 + c * 8);   // uniform -> s_load
    float4 w1 = *(const float4*)(W2 + c * 8 + 4);
    const float wv[8] = {w0.x, w0.y, w0.z, w0.w, w1.x, w1.y, w1.z, w1.w};
    const size_t coff = (size_t)(c * 8);
    const float bb = b2[0];

    int q = (blockIdx.x << 5) + g;
    if (q < nq) {
        i32x4 sv = __builtin_nontemporal_load((const i32x4*)(src + (q << 2)));
        i32x4 dv = __builtin_nontemporal_load((const i32x4*)(dst + (q << 2)));
        for (;;) {
            const int e0 = q << 2;
            const int qn = q + tg;
            const bool more = (qn < nq);
            i32x4 svn, dvn;
            if (more) {   // prefetch next quad's indices
                svn = __builtin_nontemporal_load((const i32x4*)(src + (qn << 2)));
                dvn = __builtin_nontemporal_load((const i32x4*)(dst + (qn << 2)));
            }

            // Issue all 8 row loads back-to-back.
            float4 ra0 = *(const float4*)(A  + (size_t)sv[0] * DD + coff);
            float4 rb0 = *(const float4*)(Bm + (size_t)dv[0] * DD + coff);
            float4 ra1 = *(const float4*)(A  + (size_t)sv[1] * DD + coff);
            float4 rb1 = *(const float4*)(Bm + (size_t)dv[1] * DD + coff);
            float4 ra2 = *(const float4*)(A  + (size_t)sv[2] * DD + coff);
            float4 rb2 = *(const float4*)(Bm + (size_t)dv[2] * DD + coff);
            float4 ra3 = *(const float4*)(A  + (size_t)sv[3] * DD + coff);
            float4 rb3 = *(const float4*)(Bm + (size_t)dv[3] * DD + coff);

            float acc0 = 0.f, acc1 = 0.f, acc2 = 0.f, acc3 = 0.f;
            const __half2* ah0 = (const __half2*)&ra0;
            const __half2* bh0 = (const __half2*)&rb0;
            const __half2* ah1 = (const __half2*)&ra1;
            const __half2* bh1 = (const __half2*)&rb1;
            const __half2* ah2 = (const __half2*)&ra2;
            const __half2* bh2 = (const __half2*)&rb2;
            const __half2* ah3 = (const __half2*)&ra3;
            const __half2* bh3 = (const __half2*)&rb3;
#pragma unroll
            for (int j = 0; j < 4; ++j) {
                float2 x, y;
                x = __half22float2(ah0[j]); y = __half22float2(bh0[j]);
                acc0 = fmaf(fmaxf(x.x - y.x, 0.f), wv[2 * j + 0], acc0);
                acc0 = fmaf(fmaxf(x.y - y.y, 0.f), wv[2 * j + 1], acc0);
                x = __half22float2(ah1[j]); y = __half22float2(bh1[j]);
                acc1 = fmaf(fmaxf(x.x - y.x, 0.f), wv[2 * j + 0], acc1);
                acc1 = fmaf(fmaxf(x.y - y.y, 0.f), wv[2 * j + 1], acc1);
                x = __half22float2(ah2[j]); y = __half22float2(bh2[j]);
                acc2 = fmaf(fmaxf(x.x - y.x, 0.f), wv[2 * j + 0], acc2);
                acc2 = fmaf(fmaxf(x.y - y.y, 0.f), wv[2 * j + 1], acc2);
                x = __half22float2(ah3[j]); y = __half22float2(bh3[j]);
                acc3 = fmaf(fmaxf(x.x - y.x, 0.f), wv[2 * j + 0], acc3);
                acc3 = fmaf(fmaxf(x.y - y.y, 0.f), wv[2 * j + 1], acc3);
            }

            acc0 += __shfl_xor(acc0, 1); acc1 += __shfl_xor(acc1, 1);
            acc2 += __shfl_xor(acc2, 1); acc3 += __shfl_xor(acc3, 1);
            acc0 += __shfl_xor(acc0, 2); acc1 += __shfl_xor(acc1, 2);
            acc2 += __shfl_xor(acc2, 2); acc3 += __shfl_xor(acc3, 2);
            acc0 += __shfl_xor(acc0, 4); acc1 += __shfl_xor(acc1, 4);
            acc2 += __shfl_xor(acc2, 4); acc3 += __shfl_xor(acc3, 4);

            if (c == 0) {
                fv4 r;
                r[0] = acc0 + bb; r[1] = acc1 + bb;
                r[2] = acc2 + bb; r[3] = acc3 + bb;
                __builtin_nontemporal_store(r, (fv4*)(out + e0));
            }

            if (!more) break;
            q = qn; sv = svn; dv = dvn;
        }
    }

    // Remainder edges (n_edges % 4): block 0, lane-group 0 only.
    const int rem = n_edges & 3;
    if (rem && blockIdx.x == 0 && g == 0) {
        for (int e = n_edges - rem; e < n_edges; ++e) {
            int s = src[e], d = dst[e];
            float4 ar = *(const float4*)(A  + (size_t)s * DD + coff);
            float4 br = *(const float4*)(Bm + (size_t)d * DD + coff);
            const __half2* ah = (const __half2*)&ar;
            const __half2* bh = (const __half2*)&br;
            float acc = 0.f;
#pragma unroll
            for (int j = 0; j < 4; ++j) {
                float2 x = __half22float2(ah[j]);
                float2 y = __half22float2(bh[j]);
                acc = fmaf(fmaxf(x.x - y.x, 0.f), wv[2 * j + 0], acc);
                acc = fmaf(fmaxf(x.y - y.y, 0.f), wv[2 * j + 1], acc);
            }
            acc += __shfl_xor(acc, 1);
            acc += __shfl_xor(acc, 2);
            acc += __shfl_xor(acc, 4);
            if (c == 0) out[e] = acc + bb;
        }
    }
}

extern "C" void kernel_launch(void* const* d_in, const int* in_sizes, int n_in,
                              void* d_out, int out_size, void* d_ws, size_t ws_size,
                              hipStream_t stream) {
    const float* K_h = (const float*)d_in[0];
    const float* Q_h = (const float*)d_in[1];
    const float* P_e = (const float*)d_in[2];
    const int*   src = (const int*)d_in[3];
    const int*   dst = (const int*)d_in[4];
    const float* W1  = (const float*)d_in[5];
    const float* b1  = (const float*)d_in[6];
    const float* W2  = (const float*)d_in[7];
    const float* b2  = (const float*)d_in[8];
    float* out = (float*)d_out;

    int n_nodes = in_sizes[0] / DD;
    int n_edges = in_sizes[3];

    // Workspace: A [n][64] fp16, B [n][64] fp16 (12.8 MB total)
    __half* A  = (__half*)d_ws;
    __half* Bm = A + (size_t)n_nodes * DD;

    node_transform_mfma<<<(n_nodes + NPB - 1) / NPB, 256, 0, stream>>>(
        K_h, Q_h, P_e, W1, b1, A, Bm, n_nodes);

    // Persistent grid: 2048 blocks (8 blocks/CU target), 32 lane-groups each,
    // grid-stride over edge-quads with index prefetch.
    int nq = n_edges >> 2;
    int grid = (nq + 31) >> 5;
    if (grid > 2048) grid = 2048;
    if (grid < 1) grid = 1;
    edge_score_kernel<<<grid, 256, 0, stream>>>(
        A, Bm, src, dst, W2, b2, out, n_edges);
}